// Round 2
// baseline (396.070 us; speedup 1.0000x reference)
//
#include <hip/hip_runtime.h>
#include <stdint.h>

// ---------- types & helpers ----------
typedef short bf16x8 __attribute__((ext_vector_type(8)));
typedef float f32x4 __attribute__((ext_vector_type(4)));

__device__ __forceinline__ uint16_t f2b(float f) {
    uint32_t u = __builtin_bit_cast(uint32_t, f);
    return (uint16_t)((u + 0x7fffu + ((u >> 16) & 1u)) >> 16);
}

__device__ __forceinline__ void gll16(const void* g, void* l) {
    __builtin_amdgcn_global_load_lds(
        (const __attribute__((address_space(1))) uint32_t*)(uintptr_t)g,
        (__attribute__((address_space(3))) uint32_t*)(uint32_t)(uintptr_t)l,
        16, 0, 0);
}

// triangular block id -> (bm, bn) with bn >= bm, 8x8 grid, 36 blocks
__device__ __forceinline__ void tri_map(int blk, int& bm, int& bn) {
    int m = 0, rem = blk;
    while (rem >= 8 - m) { rem -= 8 - m; m++; }
    bm = m;
    bn = m + rem;
}

// ---------- zero fp32 buffer (float4 granular) ----------
__global__ __launch_bounds__(256) void zero_f32(float4* __restrict__ p, int nvec) {
    int i = blockIdx.x * 256 + threadIdx.x;
    if (i < nvec) p[i] = float4{0.f, 0.f, 0.f, 0.f};
}

// ---------- fused convert+transpose: x f32 [4][4096][1024] ->
//            xb bf16 [16384][1024]  and  xT bf16 [4][1024][4096] ----------
__global__ __launch_bounds__(256) void cvt_tr(const float* __restrict__ x,
                                              uint16_t* __restrict__ xb,
                                              uint16_t* __restrict__ xT) {
    const int b = blockIdx.z;
    const int n0 = blockIdx.y * 64;   // token tile
    const int d0 = blockIdx.x * 64;   // feature tile
    __shared__ uint16_t tile[64][66];
    const int t = threadIdx.x;
    const float* xbase = x + (size_t)b * 4194304;
#pragma unroll
    for (int p = 0; p < 4; p++) {
        int row = p * 16 + (t >> 4);       // token-local
        int c4 = (t & 15) * 4;             // d-local
        float4 v = *(const float4*)&xbase[(size_t)(n0 + row) * 1024 + d0 + c4];
        uint16_t b0 = f2b(v.x), b1 = f2b(v.y), b2 = f2b(v.z), b3 = f2b(v.w);
        tile[row][c4 + 0] = b0;
        tile[row][c4 + 1] = b1;
        tile[row][c4 + 2] = b2;
        tile[row][c4 + 3] = b3;
        uint2 pk;
        pk.x = (uint32_t)b0 | ((uint32_t)b1 << 16);
        pk.y = (uint32_t)b2 | ((uint32_t)b3 << 16);
        *(uint2*)&xb[(size_t)(b * 4096 + n0 + row) * 1024 + d0 + c4] = pk;
    }
    __syncthreads();
    uint16_t* oT = xT + (size_t)b * 4194304;
#pragma unroll
    for (int p = 0; p < 4; p++) {
        int a = p * 16 + (t >> 4);     // d-local
        int b4 = (t & 15) * 4;         // token-local
        uint32_t x0 = tile[b4 + 0][a], x1 = tile[b4 + 1][a];
        uint32_t x2 = tile[b4 + 2][a], x3 = tile[b4 + 3][a];
        uint2 pk;
        pk.x = x0 | (x1 << 16);
        pk.y = x2 | (x3 << 16);
        *(uint2*)&oT[(size_t)(d0 + a) * 4096 + n0 + b4] = pk;
    }
}

// ---------- weight transpose: W[1024][1024] f32 -> Wt[m][e][d] bf16 ----------
struct Ptr4 { const float* p[4]; };

__global__ __launch_bounds__(256) void tr_w(Ptr4 wp, uint16_t* __restrict__ out) {
    const int m = blockIdx.z;
    const float* in = wp.p[m];
    uint16_t* o = out + (size_t)m * 1048576;
    __shared__ uint16_t tile[64][68];
    int t = threadIdx.x;
    int r0 = blockIdx.y * 64, c0 = blockIdx.x * 64;
    for (int p = 0; p < 4; p++) {
        int row = p * 16 + (t >> 4);
        int c4 = (t & 15) * 4;
        float4 v = *(const float4*)&in[(size_t)(r0 + row) * 1024 + c0 + c4];
        tile[row][c4 + 0] = f2b(v.x);
        tile[row][c4 + 1] = f2b(v.y);
        tile[row][c4 + 2] = f2b(v.z);
        tile[row][c4 + 3] = f2b(v.w);
    }
    __syncthreads();
    for (int p = 0; p < 4; p++) {
        int a = p * 16 + (t >> 4);
        int b4 = (t & 15) * 4;
        uint32_t x0 = tile[b4 + 0][a], x1 = tile[b4 + 1][a];
        uint32_t x2 = tile[b4 + 2][a], x3 = tile[b4 + 3][a];
        uint2 pk;
        pk.x = x0 | (x1 << 16);
        pk.y = x2 | (x3 << 16);
        *(uint2*)&o[(size_t)(c0 + a) * 1024 + r0 + b4] = pk;
    }
}

// ---------- gated Q projection: 512 threads, wave tile 64x32, BK=32 ----------
struct SmemG { uint16_t lA[4096]; uint16_t lB1[4096]; uint16_t lB2[4096]; };  // 24 KB

__global__ __launch_bounds__(512, 4) void proj_gate(const uint16_t* __restrict__ A,
                                                    const uint16_t* __restrict__ Wt,
                                                    uint16_t* __restrict__ Q) {
    __shared__ SmemG u;
    const int t = threadIdx.x;
    const int wave = t >> 6;
    const int lane = t & 63;
    const int m0 = blockIdx.y * 128;
    const int e0 = blockIdx.x * 128;
    const uint16_t* B1 = Wt + (size_t)e0 * 1024;                 // QL^T
    const uint16_t* B2 = Wt + 1048576 + (size_t)e0 * 1024;       // QR^T
    const int wm = (wave >> 2) * 64;     // 2 m-halves
    const int we = (wave & 3) * 32;      // 4 e-strips

    const uint16_t* gA = A + (size_t)(m0 + (t >> 2)) * 1024 + (t & 3) * 8;
    const uint16_t* gB1 = B1 + (size_t)(t >> 2) * 1024 + (t & 3) * 8;
    const uint16_t* gB2 = B2 + (size_t)(t >> 2) * 1024 + (t & 3) * 8;
    uint16_t* dA = u.lA + wave * 512;
    uint16_t* dB1 = u.lB1 + wave * 512;
    uint16_t* dB2 = u.lB2 + wave * 512;

    f32x4 acc1[4][2] = {};
    f32x4 acc2[4][2] = {};

    const int arow = wm + (lane & 15);
    const int brow = we + (lane & 15);
    const int koff = (lane >> 4) * 8;

    for (int k0 = 0; k0 < 1024; k0 += 32) {
        __syncthreads();
        gll16(gA + k0, dA);
        gll16(gB1 + k0, dB1);
        gll16(gB2 + k0, dB2);
        __syncthreads();

        bf16x8 af[4], b1f[2], b2f[2];
#pragma unroll
        for (int i = 0; i < 4; i++)
            af[i] = *(const bf16x8*)&u.lA[(arow + i * 16) * 32 + koff];
#pragma unroll
        for (int j = 0; j < 2; j++)
            b1f[j] = *(const bf16x8*)&u.lB1[(brow + j * 16) * 32 + koff];
#pragma unroll
        for (int j = 0; j < 2; j++)
            b2f[j] = *(const bf16x8*)&u.lB2[(brow + j * 16) * 32 + koff];
#pragma unroll
        for (int i = 0; i < 4; i++)
#pragma unroll
            for (int j = 0; j < 2; j++) {
                acc1[i][j] = __builtin_amdgcn_mfma_f32_16x16x32_bf16(af[i], b1f[j],
                                                                     acc1[i][j], 0, 0, 0);
                acc2[i][j] = __builtin_amdgcn_mfma_f32_16x16x32_bf16(af[i], b2f[j],
                                                                     acc2[i][j], 0, 0, 0);
            }
    }

    const int rl = (lane >> 4) * 4;
    const int cl = lane & 15;
#pragma unroll
    for (int i = 0; i < 4; i++)
#pragma unroll
        for (int j = 0; j < 2; j++)
#pragma unroll
            for (int r = 0; r < 4; r++) {
                float g = acc1[i][j][r] * acc2[i][j][r];
                Q[(size_t)(m0 + wm + i * 16 + rl + r) * 1024 + e0 + we + j * 16 + cl] = f2b(g);
            }
}

// ---------- symmetric Gram GEMM, split-K=4, triangular grid, atomic fp32 acc ----
// G32[batch][d][e] += sum_{k in ks-slice} xT[batch][d][k] * xT[batch][e][k]
// grid (36, 1, 16): x = triangular block id (bn >= bm), z = batch*4 + ks
__global__ __launch_bounds__(256) void gram_sym(const uint16_t* __restrict__ xT,
                                                float* __restrict__ G32) {
    const int z = blockIdx.z;
    const int batch = z >> 2, ks = z & 3;
    int bm, bn;
    tri_map(blockIdx.x, bm, bn);
    const uint16_t* Xb = xT + (size_t)batch * 4194304 + ks * 1024;

    __shared__ uint16_t lA[4096];
    __shared__ uint16_t lB[4096];

    const int t = threadIdx.x;
    const int wave = t >> 6;
    const int lane = t & 63;
    const int m0 = bm * 128;
    const int n0 = bn * 128;
    const int wm = (wave >> 1) * 64;
    const int wn = (wave & 1) * 64;

    const uint16_t* gA0 = Xb + (size_t)(m0 + (t >> 2)) * 4096 + (t & 3) * 8;
    const uint16_t* gB0 = Xb + (size_t)(n0 + (t >> 2)) * 4096 + (t & 3) * 8;
    uint16_t* lA0 = lA + wave * 512;
    uint16_t* lA1 = lA + 2048 + wave * 512;
    uint16_t* lB0 = lB + wave * 512;
    uint16_t* lB1 = lB + 2048 + wave * 512;

    f32x4 acc[4][4] = {};

    const int arow = wm + (lane & 15);
    const int brow = wn + (lane & 15);
    const int koff = (lane >> 4) * 8;

    for (int k0 = 0; k0 < 1024; k0 += 32) {
        __syncthreads();
        gll16(gA0 + k0, lA0);
        gll16(gA0 + (size_t)64 * 4096 + k0, lA1);
        gll16(gB0 + k0, lB0);
        gll16(gB0 + (size_t)64 * 4096 + k0, lB1);
        __syncthreads();

        bf16x8 af[4], bfr[4];
#pragma unroll
        for (int i = 0; i < 4; i++)
            af[i] = *(const bf16x8*)&lA[(arow + i * 16) * 32 + koff];
#pragma unroll
        for (int i = 0; i < 4; i++)
            bfr[i] = *(const bf16x8*)&lB[(brow + i * 16) * 32 + koff];
#pragma unroll
        for (int i = 0; i < 4; i++)
#pragma unroll
            for (int j = 0; j < 4; j++)
                acc[i][j] = __builtin_amdgcn_mfma_f32_16x16x32_bf16(af[i], bfr[j],
                                                                    acc[i][j], 0, 0, 0);
    }

    float* Gb = G32 + (size_t)batch * 1048576;
    const int crow = m0 + wm + (lane >> 4) * 4;
    const int ccol = n0 + wn + (lane & 15);
#pragma unroll
    for (int i = 0; i < 4; i++)
#pragma unroll
        for (int j = 0; j < 4; j++)
#pragma unroll
            for (int r = 0; r < 4; r++)
                unsafeAtomicAdd(&Gb[(size_t)(crow + i * 16 + r) * 1024 + ccol + j * 16],
                                acc[i][j][r]);
}

// ---------- convert G32 upper-tri -> bf16 G, mirrored (LDS transpose) ----------
// grid (36, 4, 4): x = tri block, y = 64x64 quadrant, z = batch
__global__ __launch_bounds__(256) void sym_cvt(const float* __restrict__ G32,
                                               uint16_t* __restrict__ G) {
    int bm, bn;
    tri_map(blockIdx.x, bm, bn);
    const int q = blockIdx.y;
    const int batch = blockIdx.z;
    const int r0 = bm * 128 + (q >> 1) * 64;
    const int c0 = bn * 128 + (q & 1) * 64;
    const float* Sb = G32 + (size_t)batch * 1048576;
    uint16_t* Gb = G + (size_t)batch * 1048576;
    __shared__ uint16_t tile[64][68];
    const int t = threadIdx.x;
#pragma unroll
    for (int p = 0; p < 4; p++) {
        int row = p * 16 + (t >> 4);
        int c4 = (t & 15) * 4;
        float4 v = *(const float4*)&Sb[(size_t)(r0 + row) * 1024 + c0 + c4];
        uint16_t b0 = f2b(v.x), b1 = f2b(v.y), b2 = f2b(v.z), b3 = f2b(v.w);
        tile[row][c4 + 0] = b0;
        tile[row][c4 + 1] = b1;
        tile[row][c4 + 2] = b2;
        tile[row][c4 + 3] = b3;
        uint2 pk;
        pk.x = (uint32_t)b0 | ((uint32_t)b1 << 16);
        pk.y = (uint32_t)b2 | ((uint32_t)b3 << 16);
        *(uint2*)&Gb[(size_t)(r0 + row) * 1024 + c0 + c4] = pk;   // direct (upper)
    }
    __syncthreads();
#pragma unroll
    for (int p = 0; p < 4; p++) {
        int a = p * 16 + (t >> 4);     // col in tile
        int b4 = (t & 15) * 4;         // row in tile
        uint32_t x0 = tile[b4 + 0][a], x1 = tile[b4 + 1][a];
        uint32_t x2 = tile[b4 + 2][a], x3 = tile[b4 + 3][a];
        uint2 pk;
        pk.x = x0 | (x1 << 16);
        pk.y = x2 | (x3 << 16);
        *(uint2*)&Gb[(size_t)(c0 + a) * 1024 + r0 + b4] = pk;     // mirror (lower)
    }
}

// ---------- generic 128x128-tile GEMM, K=1024, bf16 out:
//            C[z][m][n] = sum_k A[z][m][k] * Bt[n][k] ----------
__global__ __launch_bounds__(256) void gemm_nt_bf16(const uint16_t* __restrict__ A,
                                                    int lda, int az,
                                                    const uint16_t* __restrict__ Bt,
                                                    int ldb,
                                                    uint16_t* __restrict__ C,
                                                    int ldc, int cz) {
    const uint16_t* Ab = A + (size_t)blockIdx.z * az;
    uint16_t* Cb = C + (size_t)blockIdx.z * cz;

    __shared__ uint16_t lA[4096];
    __shared__ uint16_t lB[4096];

    const int t = threadIdx.x;
    const int wave = t >> 6;
    const int lane = t & 63;
    const int m0 = blockIdx.y * 128;
    const int n0 = blockIdx.x * 128;
    const int wm = (wave >> 1) * 64;
    const int wn = (wave & 1) * 64;

    const uint16_t* gA0 = Ab + (size_t)(m0 + (t >> 2)) * lda + (t & 3) * 8;
    const uint16_t* gB0 = Bt + (size_t)(n0 + (t >> 2)) * ldb + (t & 3) * 8;
    uint16_t* lA0 = lA + wave * 512;
    uint16_t* lA1 = lA + 2048 + wave * 512;
    uint16_t* lB0 = lB + wave * 512;
    uint16_t* lB1 = lB + 2048 + wave * 512;

    f32x4 acc[4][4] = {};

    const int arow = wm + (lane & 15);
    const int brow = wn + (lane & 15);
    const int koff = (lane >> 4) * 8;

    for (int k0 = 0; k0 < 1024; k0 += 32) {
        __syncthreads();
        gll16(gA0 + k0, lA0);
        gll16(gA0 + (size_t)64 * lda + k0, lA1);
        gll16(gB0 + k0, lB0);
        gll16(gB0 + (size_t)64 * ldb + k0, lB1);
        __syncthreads();

        bf16x8 af[4], bfr[4];
#pragma unroll
        for (int i = 0; i < 4; i++)
            af[i] = *(const bf16x8*)&lA[(arow + i * 16) * 32 + koff];
#pragma unroll
        for (int i = 0; i < 4; i++)
            bfr[i] = *(const bf16x8*)&lB[(brow + i * 16) * 32 + koff];
#pragma unroll
        for (int i = 0; i < 4; i++)
#pragma unroll
            for (int j = 0; j < 4; j++)
                acc[i][j] = __builtin_amdgcn_mfma_f32_16x16x32_bf16(af[i], bfr[j],
                                                                    acc[i][j], 0, 0, 0);
    }

    const int crow = m0 + wm + (lane >> 4) * 4;
    const int ccol = n0 + wn + (lane & 15);
#pragma unroll
    for (int i = 0; i < 4; i++)
#pragma unroll
        for (int j = 0; j < 4; j++)
#pragma unroll
            for (int r = 0; r < 4; r++)
                Cb[(size_t)(crow + i * 16 + r) * ldc + ccol + j * 16] = f2b(acc[i][j][r]);
}

// ---------- out GEMM: out[b][n][e] = Q @ kvT^T, fp32 out ----------
__global__ __launch_bounds__(256) void gemm_out(const uint16_t* __restrict__ A,
                                                const uint16_t* __restrict__ Bt,
                                                float* __restrict__ C) {
    const uint16_t* Ab = A + (size_t)blockIdx.z * 4194304;
    const uint16_t* Bb = Bt + (size_t)blockIdx.z * 1048576;

    __shared__ uint16_t lA[4096];
    __shared__ uint16_t lB[4096];

    const int t = threadIdx.x;
    const int wave = t >> 6;
    const int lane = t & 63;
    const int m0 = blockIdx.y * 128;
    const int n0 = blockIdx.x * 128;
    const int wm = (wave >> 1) * 64;
    const int wn = (wave & 1) * 64;

    const uint16_t* gA0 = Ab + (size_t)(m0 + (t >> 2)) * 1024 + (t & 3) * 8;
    const uint16_t* gB0 = Bb + (size_t)(n0 + (t >> 2)) * 1024 + (t & 3) * 8;
    uint16_t* lA0 = lA + wave * 512;
    uint16_t* lA1 = lA + 2048 + wave * 512;
    uint16_t* lB0 = lB + wave * 512;
    uint16_t* lB1 = lB + 2048 + wave * 512;

    f32x4 acc[4][4] = {};

    const int arow = wm + (lane & 15);
    const int brow = wn + (lane & 15);
    const int koff = (lane >> 4) * 8;

    for (int k0 = 0; k0 < 1024; k0 += 32) {
        __syncthreads();
        gll16(gA0 + k0, lA0);
        gll16(gA0 + (size_t)64 * 1024 + k0, lA1);
        gll16(gB0 + k0, lB0);
        gll16(gB0 + (size_t)64 * 1024 + k0, lB1);
        __syncthreads();

        bf16x8 af[4], bfr[4];
#pragma unroll
        for (int i = 0; i < 4; i++)
            af[i] = *(const bf16x8*)&lA[(arow + i * 16) * 32 + koff];
#pragma unroll
        for (int i = 0; i < 4; i++)
            bfr[i] = *(const bf16x8*)&lB[(brow + i * 16) * 32 + koff];
#pragma unroll
        for (int i = 0; i < 4; i++)
#pragma unroll
            for (int j = 0; j < 4; j++)
                acc[i][j] = __builtin_amdgcn_mfma_f32_16x16x32_bf16(af[i], bfr[j],
                                                                    acc[i][j], 0, 0, 0);
    }

    float* Cb = C + (size_t)blockIdx.z * 4194304;
    const int crow = m0 + wm + (lane >> 4) * 4;
    const int ccol = n0 + wn + (lane & 15);
#pragma unroll
    for (int i = 0; i < 4; i++)
#pragma unroll
        for (int j = 0; j < 4; j++)
#pragma unroll
            for (int r = 0; r < 4; r++)
                Cb[(size_t)(crow + i * 16 + r) * 1024 + ccol + j * 16] = acc[i][j][r];
}

// ---------- launch ----------
extern "C" void kernel_launch(void* const* d_in, const int* in_sizes, int n_in,
                              void* d_out, int out_size, void* d_ws, size_t ws_size,
                              hipStream_t stream) {
    const float* x = (const float*)d_in[0];

    uint16_t* ws  = (uint16_t*)d_ws;
    uint16_t* xb  = ws;                        // [0,32MB)    x bf16 row-major
    uint16_t* xT  = ws + 16777216;             // [32,64MB)   x^T bf16 [4][1024][4096]
    uint16_t* Wt  = ws + 33554432;             // [64,72MB)   W^T x4 bf16
    uint16_t* Q   = ws + 37748736;             // [72,104MB)  gated query bf16
    float*    G32 = (float*)(ws + 54525952);   // [104,120MB) fp32 Gram accumulator
    uint16_t* G   = ws + 71303168;             // [136,144MB) G = x^T x bf16 (full)
    uint16_t* H   = ws + 75497472;             // [144,152MB) H = Wv^T G  [1024][4096]
    uint16_t* kvT = ws + 79691776;             // [152,160MB) kv^T bf16 [4][1024][1024]

    // 1. x -> xb (row-major bf16) + xT (transposed bf16), one pass over x
    cvt_tr<<<dim3(16, 64, 4), 256, 0, stream>>>(x, xb, xT);

    // 2. weights -> W^T bf16 (ql, qr, k, v)
    Ptr4 wp;
    wp.p[0] = (const float*)d_in[1];
    wp.p[1] = (const float*)d_in[2];
    wp.p[2] = (const float*)d_in[3];
    wp.p[3] = (const float*)d_in[4];
    tr_w<<<dim3(16, 16, 4), 256, 0, stream>>>(wp, Wt);

    // 3. zero the Gram accumulator (16 MB fp32)
    zero_f32<<<4096, 256, 0, stream>>>((float4*)G32, 1048576);

    // 4. gated query projection
    proj_gate<<<dim3(8, 128), 512, 0, stream>>>(xb, Wt, Q);

    // 5. symmetric Gram: upper-triangular 128^2 tiles, split-K=4, atomic fp32 acc
    gram_sym<<<dim3(36, 1, 16), 256, 0, stream>>>(xT, G32);

    // 6. G32 upper -> bf16 G with mirror (G symmetric)
    sym_cvt<<<dim3(36, 4, 4), 256, 0, stream>>>(G32, G);

    // 7. H = Wv^T @ G  (M=1024 e, N=4096 (b,c), K=1024 d; G symmetric -> rows as B)
    gemm_nt_bf16<<<dim3(32, 8, 1), 256, 0, stream>>>(Wt + 3 * 1048576, 1024, 0,
                                                     G, 1024, H, 4096, 0);

    // 8. kvT[b] = H[:, b*1024:(b+1)*1024] @ Wk  (A = H slice, B = Wk^T)
    gemm_nt_bf16<<<dim3(8, 8, 4), 256, 0, stream>>>(H, 4096, 1024,
                                                    Wt + 2 * 1048576, 1024,
                                                    kvT, 1024, 1048576);

    // 9. out = Q @ kvT^T, fp32
    gemm_out<<<dim3(8, 32, 4), 256, 0, stream>>>(Q, kvT, (float*)d_out);
}

// Round 3
// 372.563 us; speedup vs baseline: 1.0631x; 1.0631x over previous
//
#include <hip/hip_runtime.h>
#include <stdint.h>

// ---------- types & helpers ----------
typedef short bf16x8 __attribute__((ext_vector_type(8)));
typedef float f32x4 __attribute__((ext_vector_type(4)));

__device__ __forceinline__ uint16_t f2b(float f) {
    uint32_t u = __builtin_bit_cast(uint32_t, f);
    return (uint16_t)((u + 0x7fffu + ((u >> 16) & 1u)) >> 16);
}

__device__ __forceinline__ void gll16(const void* g, void* l) {
    __builtin_amdgcn_global_load_lds(
        (const __attribute__((address_space(1))) uint32_t*)(uintptr_t)g,
        (__attribute__((address_space(3))) uint32_t*)(uint32_t)(uintptr_t)l,
        16, 0, 0);
}

// ---------- fused convert+transpose: x f32 [4][4096][1024] ->
//            xb bf16 [16384][1024]  and  xT bf16 [4][1024][4096] ----------
__global__ __launch_bounds__(256) void cvt_tr(const float* __restrict__ x,
                                              uint16_t* __restrict__ xb,
                                              uint16_t* __restrict__ xT) {
    const int b = blockIdx.z;
    const int n0 = blockIdx.y * 64;   // token tile
    const int d0 = blockIdx.x * 64;   // feature tile
    __shared__ uint16_t tile[64][66];
    const int t = threadIdx.x;
    const float* xbase = x + (size_t)b * 4194304;
#pragma unroll
    for (int p = 0; p < 4; p++) {
        int row = p * 16 + (t >> 4);       // token-local
        int c4 = (t & 15) * 4;             // d-local
        float4 v = *(const float4*)&xbase[(size_t)(n0 + row) * 1024 + d0 + c4];
        uint16_t b0 = f2b(v.x), b1 = f2b(v.y), b2 = f2b(v.z), b3 = f2b(v.w);
        tile[row][c4 + 0] = b0;
        tile[row][c4 + 1] = b1;
        tile[row][c4 + 2] = b2;
        tile[row][c4 + 3] = b3;
        uint2 pk;
        pk.x = (uint32_t)b0 | ((uint32_t)b1 << 16);
        pk.y = (uint32_t)b2 | ((uint32_t)b3 << 16);
        *(uint2*)&xb[(size_t)(b * 4096 + n0 + row) * 1024 + d0 + c4] = pk;
    }
    __syncthreads();
    uint16_t* oT = xT + (size_t)b * 4194304;
#pragma unroll
    for (int p = 0; p < 4; p++) {
        int a = p * 16 + (t >> 4);     // d-local
        int b4 = (t & 15) * 4;         // token-local
        uint32_t x0 = tile[b4 + 0][a], x1 = tile[b4 + 1][a];
        uint32_t x2 = tile[b4 + 2][a], x3 = tile[b4 + 3][a];
        uint2 pk;
        pk.x = x0 | (x1 << 16);
        pk.y = x2 | (x3 << 16);
        *(uint2*)&oT[(size_t)(d0 + a) * 4096 + n0 + b4] = pk;
    }
}

// ---------- weight transpose: W[1024][1024] f32 -> Wt[m][e][d] bf16 ----------
struct Ptr4 { const float* p[4]; };

__global__ __launch_bounds__(256) void tr_w(Ptr4 wp, uint16_t* __restrict__ out) {
    const int m = blockIdx.z;
    const float* in = wp.p[m];
    uint16_t* o = out + (size_t)m * 1048576;
    __shared__ uint16_t tile[64][68];
    int t = threadIdx.x;
    int r0 = blockIdx.y * 64, c0 = blockIdx.x * 64;
    for (int p = 0; p < 4; p++) {
        int row = p * 16 + (t >> 4);
        int c4 = (t & 15) * 4;
        float4 v = *(const float4*)&in[(size_t)(r0 + row) * 1024 + c0 + c4];
        tile[row][c4 + 0] = f2b(v.x);
        tile[row][c4 + 1] = f2b(v.y);
        tile[row][c4 + 2] = f2b(v.z);
        tile[row][c4 + 3] = f2b(v.w);
    }
    __syncthreads();
    for (int p = 0; p < 4; p++) {
        int a = p * 16 + (t >> 4);
        int b4 = (t & 15) * 4;
        uint32_t x0 = tile[b4 + 0][a], x1 = tile[b4 + 1][a];
        uint32_t x2 = tile[b4 + 2][a], x3 = tile[b4 + 3][a];
        uint2 pk;
        pk.x = x0 | (x1 << 16);
        pk.y = x2 | (x3 << 16);
        *(uint2*)&o[(size_t)(c0 + a) * 1024 + r0 + b4] = pk;
    }
}

// ---------- 8-phase dual-B gated projection ----------
// BM=256 (m), BN=128 (e) with TWO B matrices (QL^T, QR^T), BK=64, 512 thr,
// 8 waves as 4M x 2N (per-wave 64x64 per matrix).
// LDS 128 KB: 2 bufs x { A 256x64 (32KB) | B1 128x64 (16KB) | B2 128x64 (16KB) }.
// T2: XOR-swizzle byte^=((row&7)<<4), applied on PRE-SWIZZLED global source
// (gll16 dest stays linear) and on ds_read addresses (rule #21, involution).
// T3/T4: double-buffer, counted vmcnt(8) — loads stay in flight across barriers.
// T5: setprio around each 16-MFMA cluster.
__global__ __launch_bounds__(512, 2) void proj_gate8(const uint16_t* __restrict__ A,
                                                     const uint16_t* __restrict__ Wt,
                                                     uint16_t* __restrict__ Q) {
    __shared__ uint16_t lds[65536];   // 128 KB
    const int t = threadIdx.x;
    const int wave = t >> 6;
    const int lane = t & 63;
    const int m0 = blockIdx.y * 256;
    const int e0 = blockIdx.x * 128;
    const uint16_t* B1 = Wt + (size_t)e0 * 1024;             // QL^T rows e0..e0+127
    const uint16_t* B2 = Wt + 1048576 + (size_t)e0 * 1024;   // QR^T
    const int wm = (wave >> 1) * 64;   // wave m-offset (4 waves along m)
    const int wn = (wave & 1) * 64;    // wave n-offset (2 waves along n)

    // ---- staging source (pre-swizzled k within each 128-B row) ----
    const int srow = t >> 3;                            // 0..63
    const int ske = ((t & 7) ^ (srow & 7)) * 8;         // swizzled k-element
    const uint16_t* gA  = A  + (size_t)(m0 + srow) * 1024 + ske;
    const uint16_t* gB1 = B1 + (size_t)srow * 1024 + ske;
    const uint16_t* gB2 = B2 + (size_t)srow * 1024 + ske;

    auto STAGE = [&](int kt, int buf) {
        const int kk = kt * 64;
        uint16_t* db = lds + buf * 32768 + (wave << 9);  // wave-uniform + lane*16B
        gll16(gA + kk,          db);            // A rows   0..63
        gll16(gA + 65536 + kk,  db + 4096);     // A rows  64..127
        gll16(gA + 131072 + kk, db + 8192);     // A rows 128..191
        gll16(gA + 196608 + kk, db + 12288);    // A rows 192..255
        gll16(gB1 + kk,         db + 16384);    // B1 rows  0..63
        gll16(gB1 + 65536 + kk, db + 20480);    // B1 rows 64..127
        gll16(gB2 + kk,         db + 24576);    // B2 rows  0..63
        gll16(gB2 + 65536 + kk, db + 28672);    // B2 rows 64..127
    };

    // ---- read-side swizzled element offsets (XOR key = (lane&7)<<4 bytes) ----
    const int l7x16 = (lane & 7) << 4;
    const int hi16 = (lane >> 4) << 4;                 // byte offset within k-slot
    const int es0 = (hi16 ^ l7x16) >> 1;               // k-slot 0, elements
    const int es1 = ((64 + hi16) ^ l7x16) >> 1;        // k-slot 1, elements
    int ar[4], br[4];
#pragma unroll
    for (int i = 0; i < 4; i++) ar[i] = (wm + i * 16 + (lane & 15)) * 64;
#pragma unroll
    for (int j = 0; j < 4; j++) br[j] = (wn + j * 16 + (lane & 15)) * 64;

    f32x4 acc1[4][4] = {};
    f32x4 acc2[4][4] = {};

    // ---- prologue: 2 tiles in flight, wait for tile 0 only ----
    STAGE(0, 0);
    STAGE(1, 1);
    asm volatile("s_waitcnt vmcnt(8)" ::: "memory");
    __builtin_amdgcn_s_barrier();

    for (int kt = 0; kt < 16; ++kt) {
        const int buf = kt & 1;
        const uint16_t* lb = lds + buf * 32768;
        bf16x8 af[4], bq[4];

        // phase 1: A + B1 (k-slot 0) -> acc1
#pragma unroll
        for (int i = 0; i < 4; i++) af[i] = *(const bf16x8*)&lb[ar[i] + es0];
#pragma unroll
        for (int j = 0; j < 4; j++) bq[j] = *(const bf16x8*)&lb[16384 + br[j] + es0];
        __builtin_amdgcn_s_setprio(1);
#pragma unroll
        for (int i = 0; i < 4; i++)
#pragma unroll
            for (int j = 0; j < 4; j++)
                acc1[i][j] = __builtin_amdgcn_mfma_f32_16x16x32_bf16(af[i], bq[j],
                                                                     acc1[i][j], 0, 0, 0);
        __builtin_amdgcn_s_setprio(0);

        // phase 2: B2 (k-slot 0) -> acc2
#pragma unroll
        for (int j = 0; j < 4; j++) bq[j] = *(const bf16x8*)&lb[24576 + br[j] + es0];
        __builtin_amdgcn_s_setprio(1);
#pragma unroll
        for (int i = 0; i < 4; i++)
#pragma unroll
            for (int j = 0; j < 4; j++)
                acc2[i][j] = __builtin_amdgcn_mfma_f32_16x16x32_bf16(af[i], bq[j],
                                                                     acc2[i][j], 0, 0, 0);
        __builtin_amdgcn_s_setprio(0);

        // phase 3: A + B1 (k-slot 1) -> acc1
#pragma unroll
        for (int i = 0; i < 4; i++) af[i] = *(const bf16x8*)&lb[ar[i] + es1];
#pragma unroll
        for (int j = 0; j < 4; j++) bq[j] = *(const bf16x8*)&lb[16384 + br[j] + es1];
        __builtin_amdgcn_s_setprio(1);
#pragma unroll
        for (int i = 0; i < 4; i++)
#pragma unroll
            for (int j = 0; j < 4; j++)
                acc1[i][j] = __builtin_amdgcn_mfma_f32_16x16x32_bf16(af[i], bq[j],
                                                                     acc1[i][j], 0, 0, 0);
        __builtin_amdgcn_s_setprio(0);

        // phase 4: B2 (k-slot 1) -> acc2
#pragma unroll
        for (int j = 0; j < 4; j++) bq[j] = *(const bf16x8*)&lb[24576 + br[j] + es1];
        __builtin_amdgcn_s_setprio(1);
#pragma unroll
        for (int i = 0; i < 4; i++)
#pragma unroll
            for (int j = 0; j < 4; j++)
                acc2[i][j] = __builtin_amdgcn_mfma_f32_16x16x32_bf16(af[i], bq[j],
                                                                     acc2[i][j], 0, 0, 0);
        __builtin_amdgcn_s_setprio(0);

        // all ds_reads of this buffer complete before anyone overwrites it
        asm volatile("s_waitcnt lgkmcnt(0)" ::: "memory");
        __builtin_amdgcn_sched_barrier(0);
        __builtin_amdgcn_s_barrier();
        if (kt < 14) {
            STAGE(kt + 2, buf);                          // refill just-freed buffer
            asm volatile("s_waitcnt vmcnt(8)" ::: "memory");  // tile kt+1 landed
        } else {
            asm volatile("s_waitcnt vmcnt(0)" ::: "memory");  // drain tail
        }
        __builtin_amdgcn_s_barrier();
    }

    // ---- epilogue: register gate, bf16 store ----
    const int rl = (lane >> 4) * 4;
    const int cl = lane & 15;
#pragma unroll
    for (int i = 0; i < 4; i++)
#pragma unroll
        for (int j = 0; j < 4; j++)
#pragma unroll
            for (int r = 0; r < 4; r++) {
                float g = acc1[i][j][r] * acc2[i][j][r];
                Q[(size_t)(m0 + wm + i * 16 + rl + r) * 1024 + e0 + wn + j * 16 + cl] = f2b(g);
            }
}

// ---------- split-K(2) Gram GEMM: P[z] = xT-slice @ xT-slice^T, fp32 partials ----
__global__ __launch_bounds__(256) void gemm_kv_splitk(const uint16_t* __restrict__ VT,
                                                      const uint16_t* __restrict__ KT,
                                                      float* __restrict__ P) {
    const int z = blockIdx.z;
    const int batch = z >> 1, ks = z & 1;
    const uint16_t* Ab = VT + (size_t)batch * 4194304 + ks * 2048;
    const uint16_t* Bb = KT + (size_t)batch * 4194304 + ks * 2048;

    __shared__ uint16_t lA[4096];
    __shared__ uint16_t lB[4096];

    const int t = threadIdx.x;
    const int wave = t >> 6;
    const int lane = t & 63;
    const int m0 = blockIdx.y * 128;
    const int n0 = blockIdx.x * 128;
    const int wm = (wave >> 1) * 64;
    const int wn = (wave & 1) * 64;

    const uint16_t* gA0 = Ab + (size_t)(m0 + (t >> 2)) * 4096 + (t & 3) * 8;
    const uint16_t* gB0 = Bb + (size_t)(n0 + (t >> 2)) * 4096 + (t & 3) * 8;
    uint16_t* lA0 = lA + wave * 512;
    uint16_t* lA1 = lA + 2048 + wave * 512;
    uint16_t* lB0 = lB + wave * 512;
    uint16_t* lB1 = lB + 2048 + wave * 512;

    f32x4 acc[4][4] = {};

    const int arow = wm + (lane & 15);
    const int brow = wn + (lane & 15);
    const int koff = (lane >> 4) * 8;

    for (int k0 = 0; k0 < 2048; k0 += 32) {
        __syncthreads();
        gll16(gA0 + k0, lA0);
        gll16(gA0 + (size_t)64 * 4096 + k0, lA1);
        gll16(gB0 + k0, lB0);
        gll16(gB0 + (size_t)64 * 4096 + k0, lB1);
        __syncthreads();

        bf16x8 af[4], bfr[4];
#pragma unroll
        for (int i = 0; i < 4; i++)
            af[i] = *(const bf16x8*)&lA[(arow + i * 16) * 32 + koff];
#pragma unroll
        for (int i = 0; i < 4; i++)
            bfr[i] = *(const bf16x8*)&lB[(brow + i * 16) * 32 + koff];
#pragma unroll
        for (int i = 0; i < 4; i++)
#pragma unroll
            for (int j = 0; j < 4; j++)
                acc[i][j] = __builtin_amdgcn_mfma_f32_16x16x32_bf16(af[i], bfr[j],
                                                                    acc[i][j], 0, 0, 0);
    }

    float* Pb = P + (size_t)z * 1048576;
    const int crow = m0 + wm + (lane >> 4) * 4;
    const int ccol = n0 + wn + (lane & 15);
#pragma unroll
    for (int i = 0; i < 4; i++)
#pragma unroll
        for (int j = 0; j < 4; j++)
#pragma unroll
            for (int r = 0; r < 4; r++)
                Pb[(size_t)(crow + i * 16 + r) * 1024 + ccol + j * 16] = acc[i][j][r];
}

// ---------- reduce 2 fp32 partials -> bf16 (G = x^T x per batch) ----------
__global__ __launch_bounds__(256) void reduce_kv(const float4* __restrict__ P,
                                                 uint2* __restrict__ G) {
    int i = blockIdx.x * 256 + threadIdx.x;
    int b = i >> 18;
    int r = i & 262143;
    const float4* base = P + (size_t)b * 524288 + r;
    float4 s0 = base[0];
    float4 s1 = base[262144];
    float x = s0.x + s1.x;
    float y = s0.y + s1.y;
    float zz = s0.z + s1.z;
    float w = s0.w + s1.w;
    uint2 o;
    o.x = (uint32_t)f2b(x) | ((uint32_t)f2b(y) << 16);
    o.y = (uint32_t)f2b(zz) | ((uint32_t)f2b(w) << 16);
    G[i] = o;
}

// ---------- generic 128x128-tile GEMM, K=1024, bf16 out:
//            C[z][m][n] = sum_k A[z][m][k] * Bt[n][k] ----------
__global__ __launch_bounds__(256) void gemm_nt_bf16(const uint16_t* __restrict__ A,
                                                    int lda, int az,
                                                    const uint16_t* __restrict__ Bt,
                                                    int ldb,
                                                    uint16_t* __restrict__ C,
                                                    int ldc, int cz) {
    const uint16_t* Ab = A + (size_t)blockIdx.z * az;
    uint16_t* Cb = C + (size_t)blockIdx.z * cz;

    __shared__ uint16_t lA[4096];
    __shared__ uint16_t lB[4096];

    const int t = threadIdx.x;
    const int wave = t >> 6;
    const int lane = t & 63;
    const int m0 = blockIdx.y * 128;
    const int n0 = blockIdx.x * 128;
    const int wm = (wave >> 1) * 64;
    const int wn = (wave & 1) * 64;

    const uint16_t* gA0 = Ab + (size_t)(m0 + (t >> 2)) * lda + (t & 3) * 8;
    const uint16_t* gB0 = Bt + (size_t)(n0 + (t >> 2)) * ldb + (t & 3) * 8;
    uint16_t* lA0 = lA + wave * 512;
    uint16_t* lA1 = lA + 2048 + wave * 512;
    uint16_t* lB0 = lB + wave * 512;
    uint16_t* lB1 = lB + 2048 + wave * 512;

    f32x4 acc[4][4] = {};

    const int arow = wm + (lane & 15);
    const int brow = wn + (lane & 15);
    const int koff = (lane >> 4) * 8;

    for (int k0 = 0; k0 < 1024; k0 += 32) {
        __syncthreads();
        gll16(gA0 + k0, lA0);
        gll16(gA0 + (size_t)64 * lda + k0, lA1);
        gll16(gB0 + k0, lB0);
        gll16(gB0 + (size_t)64 * ldb + k0, lB1);
        __syncthreads();

        bf16x8 af[4], bfr[4];
#pragma unroll
        for (int i = 0; i < 4; i++)
            af[i] = *(const bf16x8*)&lA[(arow + i * 16) * 32 + koff];
#pragma unroll
        for (int i = 0; i < 4; i++)
            bfr[i] = *(const bf16x8*)&lB[(brow + i * 16) * 32 + koff];
#pragma unroll
        for (int i = 0; i < 4; i++)
#pragma unroll
            for (int j = 0; j < 4; j++)
                acc[i][j] = __builtin_amdgcn_mfma_f32_16x16x32_bf16(af[i], bfr[j],
                                                                    acc[i][j], 0, 0, 0);
    }

    const int crow = m0 + wm + (lane >> 4) * 4;
    const int ccol = n0 + wn + (lane & 15);
#pragma unroll
    for (int i = 0; i < 4; i++)
#pragma unroll
        for (int j = 0; j < 4; j++)
#pragma unroll
            for (int r = 0; r < 4; r++)
                Cb[(size_t)(crow + i * 16 + r) * ldc + ccol + j * 16] = f2b(acc[i][j][r]);
}

// ---------- out GEMM: out[b][n][e] = Q @ kvT^T, fp32 out ----------
__global__ __launch_bounds__(256) void gemm_out(const uint16_t* __restrict__ A,
                                                const uint16_t* __restrict__ Bt,
                                                float* __restrict__ C) {
    const uint16_t* Ab = A + (size_t)blockIdx.z * 4194304;
    const uint16_t* Bb = Bt + (size_t)blockIdx.z * 1048576;

    __shared__ uint16_t lA[4096];
    __shared__ uint16_t lB[4096];

    const int t = threadIdx.x;
    const int wave = t >> 6;
    const int lane = t & 63;
    const int m0 = blockIdx.y * 128;
    const int n0 = blockIdx.x * 128;
    const int wm = (wave >> 1) * 64;
    const int wn = (wave & 1) * 64;

    const uint16_t* gA0 = Ab + (size_t)(m0 + (t >> 2)) * 1024 + (t & 3) * 8;
    const uint16_t* gB0 = Bb + (size_t)(n0 + (t >> 2)) * 1024 + (t & 3) * 8;
    uint16_t* lA0 = lA + wave * 512;
    uint16_t* lA1 = lA + 2048 + wave * 512;
    uint16_t* lB0 = lB + wave * 512;
    uint16_t* lB1 = lB + 2048 + wave * 512;

    f32x4 acc[4][4] = {};

    const int arow = wm + (lane & 15);
    const int brow = wn + (lane & 15);
    const int koff = (lane >> 4) * 8;

    for (int k0 = 0; k0 < 1024; k0 += 32) {
        __syncthreads();
        gll16(gA0 + k0, lA0);
        gll16(gA0 + (size_t)64 * 1024 + k0, lA1);
        gll16(gB0 + k0, lB0);
        gll16(gB0 + (size_t)64 * 1024 + k0, lB1);
        __syncthreads();

        bf16x8 af[4], bfr[4];
#pragma unroll
        for (int i = 0; i < 4; i++)
            af[i] = *(const bf16x8*)&lA[(arow + i * 16) * 32 + koff];
#pragma unroll
        for (int i = 0; i < 4; i++)
            bfr[i] = *(const bf16x8*)&lB[(brow + i * 16) * 32 + koff];
#pragma unroll
        for (int i = 0; i < 4; i++)
#pragma unroll
            for (int j = 0; j < 4; j++)
                acc[i][j] = __builtin_amdgcn_mfma_f32_16x16x32_bf16(af[i], bfr[j],
                                                                    acc[i][j], 0, 0, 0);
    }

    float* Cb = C + (size_t)blockIdx.z * 4194304;
    const int crow = m0 + wm + (lane >> 4) * 4;
    const int ccol = n0 + wn + (lane & 15);
#pragma unroll
    for (int i = 0; i < 4; i++)
#pragma unroll
        for (int j = 0; j < 4; j++)
#pragma unroll
            for (int r = 0; r < 4; r++)
                Cb[(size_t)(crow + i * 16 + r) * 1024 + ccol + j * 16] = acc[i][j][r];
}

// ---------- launch ----------
extern "C" void kernel_launch(void* const* d_in, const int* in_sizes, int n_in,
                              void* d_out, int out_size, void* d_ws, size_t ws_size,
                              hipStream_t stream) {
    const float* x = (const float*)d_in[0];

    uint16_t* ws  = (uint16_t*)d_ws;
    uint16_t* xb  = ws;                        // [0,32MB)    x bf16 row-major
    uint16_t* xT  = ws + 16777216;             // [32,64MB)   x^T bf16 [4][1024][4096]
    uint16_t* Wt  = ws + 33554432;             // [64,72MB)   W^T x4 bf16
    uint16_t* Q   = ws + 37748736;             // [72,104MB)  gated query bf16
    float*    P   = (float*)(ws + 54525952);   // [104,136MB) fp32 Gram partials
    uint16_t* G   = ws + 71303168;             // [136,144MB) G = x^T x bf16
    uint16_t* H   = ws + 75497472;             // [144,152MB) H = Wv^T G  [1024][4096]
    uint16_t* kvT = ws + 79691776;             // [152,160MB) kv^T bf16 [4][1024][1024]

    // 1. x -> xb (row-major bf16) + xT (transposed bf16), one pass over x
    cvt_tr<<<dim3(16, 64, 4), 256, 0, stream>>>(x, xb, xT);

    // 2. weights -> W^T bf16 (ql, qr, k, v)
    Ptr4 wp;
    wp.p[0] = (const float*)d_in[1];
    wp.p[1] = (const float*)d_in[2];
    wp.p[2] = (const float*)d_in[3];
    wp.p[3] = (const float*)d_in[4];
    tr_w<<<dim3(16, 16, 4), 256, 0, stream>>>(wp, Wt);

    // 3. gated query projection: 8-phase 256x128 dual-B pipeline
    proj_gate8<<<dim3(8, 64), 512, 0, stream>>>(xb, Wt, Q);

    // 4. Gram matrix partials: G = x^T x per batch (split-K = 2)
    gemm_kv_splitk<<<dim3(8, 8, 8), 256, 0, stream>>>(xT, xT, P);

    // 5. reduce partials -> G bf16
    reduce_kv<<<4096, 256, 0, stream>>>((const float4*)P, (uint2*)G);

    // 6. H = Wv^T @ G  (M=1024 e, N=4096 (b,c), K=1024 d; G symmetric -> rows as B)
    gemm_nt_bf16<<<dim3(32, 8, 1), 256, 0, stream>>>(Wt + 3 * 1048576, 1024, 0,
                                                     G, 1024, H, 4096, 0);

    // 7. kvT[b] = H[:, b*1024:(b+1)*1024] @ Wk  (A = H slice, B = Wk^T)
    gemm_nt_bf16<<<dim3(8, 8, 4), 256, 0, stream>>>(H, 4096, 1024,
                                                    Wt + 2 * 1048576, 1024,
                                                    kvT, 1024, 1048576);

    // 8. out = Q @ kvT^T, fp32
    gemm_out<<<dim3(8, 32, 4), 256, 0, stream>>>(Q, kvT, (float*)d_out);
}